// Round 3
// baseline (558.270 us; speedup 1.0000x reference)
//
#include <hip/hip_runtime.h>
#include <hip/hip_cooperative_groups.h>
#include <math.h>

#define SEQ  2048
#define ROWS 4096
#define D0   512
#define D1   64

namespace cg = cooperative_groups;

typedef short bf8 __attribute__((ext_vector_type(8)));   // 8 bf16 = 4 VGPRs
typedef float f4  __attribute__((ext_vector_type(4)));   // MFMA acc

// ---------------------------------------------------------------------------
// fp32 -> bf16 hi/lo split (RNE)
// ---------------------------------------------------------------------------
__device__ __forceinline__ unsigned short f2bf(float f) {
    unsigned u = __float_as_uint(f);
    return (unsigned short)((u + 0x7fffu + ((u >> 16) & 1u)) >> 16);
}
__device__ __forceinline__ void hilo(float f, unsigned short& h, unsigned short& l) {
    h = f2bf(f);
    float fh = __uint_as_float((unsigned)h << 16);
    l = f2bf(f - fh);
}
__device__ __forceinline__ void cv4(unsigned short* dh, unsigned short* dl, int idx, float4 v) {
    ushort4 hv, lv;
    hilo(v.x, hv.x, lv.x); hilo(v.y, hv.y, lv.y);
    hilo(v.z, hv.z, lv.z); hilo(v.w, hv.w, lv.w);
    *(ushort4*)(dh + idx) = hv;
    *(ushort4*)(dl + idx) = lv;
}

// async global->LDS 16B copy (dest must be wave-uniform base + lane*16)
__device__ __forceinline__ void async16(const void* g, void* l) {
    __builtin_amdgcn_global_load_lds(
        (const __attribute__((address_space(1))) unsigned int*)g,
        (__attribute__((address_space(3))) unsigned int*)l, 16, 0, 0);
}

// ---------------------------------------------------------------------------
// bf16x3 MFMA GEMM tile: C[bm:bm+128, bn:bn+64] over K-range [bz*Ks, +Ks).
// 256 thr = 4 waves; wave wv owns rows [wv*32, +32) x all 64 n.
// LDS dest pattern verified wave-uniform (lo = base + ln*8 ushorts = lane*16B).
// ---------------------------------------------------------------------------
__device__ __forceinline__ void gemm_tile(
        const unsigned short* __restrict__ Ah, const unsigned short* __restrict__ Al,
        const unsigned short* __restrict__ Wh, const unsigned short* __restrict__ Wl,
        float* __restrict__ C, int M, int N, int K, int Ks, int bx, int by, int bz,
        unsigned short* aH, unsigned short* aL, unsigned short* wH, unsigned short* wL) {
    const int tid = threadIdx.x;
    const int wv  = tid >> 6;
    const int ln  = tid & 63;
    const int lm  = ln & 15;
    const int lq  = ln >> 4;
    const int bm  = by * 128;
    const int bn  = bx * 64;
    const int k0  = bz * Ks;
    C += (size_t)bz * M * N;

    f4 acc[2][4] = {};

    for (int kt = 0; kt < Ks; kt += 64) {
        const int kg = k0 + kt;
        __syncthreads();   // protect LDS vs previous iteration / previous stage
#pragma unroll
        for (int i = 0; i < 4; ++i) {
            int c = i * 64 + ln;
            int row = wv * 32 + (c >> 3);
            int ch  = c & 7;
            size_t go = (size_t)(bm + row) * K + kg + ch * 8;
            int    lo = row * 64 + ch * 8;
            async16(Ah + go, aH + lo);
            async16(Al + go, aL + lo);
        }
#pragma unroll
        for (int i = 0; i < 2; ++i) {
            int c = i * 64 + ln;
            int row = wv * 16 + (c >> 3);
            int ch  = c & 7;
            size_t go = (size_t)(bn + row) * K + kg + ch * 8;
            int    lo = row * 64 + ch * 8;
            async16(Wh + go, wH + lo);
            async16(Wl + go, wL + lo);
        }
        __syncthreads();   // vmcnt drained by compiler before barrier

#pragma unroll
        for (int kk = 0; kk < 2; ++kk) {
            bf8 ah[2], al[2], bh[4], bl[4];
#pragma unroll
            for (int t = 0; t < 2; ++t) {
                int off = (wv * 32 + t * 16 + lm) * 64 + kk * 32 + lq * 8;
                ah[t] = *(const bf8*)(aH + off);
                al[t] = *(const bf8*)(aL + off);
            }
#pragma unroll
            for (int u = 0; u < 4; ++u) {
                int off = (u * 16 + lm) * 64 + kk * 32 + lq * 8;
                bh[u] = *(const bf8*)(wH + off);
                bl[u] = *(const bf8*)(wL + off);
            }
#pragma unroll
            for (int t = 0; t < 2; ++t)
#pragma unroll
                for (int u = 0; u < 4; ++u) {
                    acc[t][u] = __builtin_amdgcn_mfma_f32_16x16x32_bf16(ah[t], bh[u], acc[t][u], 0, 0, 0);
                    acc[t][u] = __builtin_amdgcn_mfma_f32_16x16x32_bf16(ah[t], bl[u], acc[t][u], 0, 0, 0);
                    acc[t][u] = __builtin_amdgcn_mfma_f32_16x16x32_bf16(al[t], bh[u], acc[t][u], 0, 0, 0);
                }
        }
    }

    // C/D layout (verified): col = lane&15, row = quad*4 + reg
#pragma unroll
    for (int t = 0; t < 2; ++t)
#pragma unroll
        for (int u = 0; u < 4; ++u) {
            int row = bm + wv * 32 + t * 16 + lq * 4;
            int col = bn + u * 16 + lm;
#pragma unroll
            for (int r = 0; r < 4; ++r)
                C[(size_t)(row + r) * N + col] = acc[t][u][r];
        }
}

// ---------------------------------------------------------------------------
// LN + rank-1 RN epilogue, wave-per-row (no block barriers).
// Each of the 1024 global waves does 4 rows (4096 total). Lane l owns 8 cols.
// ---------------------------------------------------------------------------
__device__ __forceinline__ void lnrn_stage(
        const float* __restrict__ Y, int ldy,
        const float* __restrict__ RES, int ldr,
        const float* __restrict__ g, const float* __restrict__ be,
        const float* __restrict__ Bb, const float* __restrict__ AaT,
        float* __restrict__ outf,
        unsigned short* __restrict__ outh, unsigned short* __restrict__ outl) {
    const int wgid = blockIdx.x * 4 + (threadIdx.x >> 6);
    const int l = threadIdx.x & 63;
    const int c = l * 8;
    for (int rr = 0; rr < 4; ++rr) {
        const int row = wgid + rr * 1024;
        const float* y = Y + (size_t)row * ldy + c;
        float4 y0 = *(const float4*)y;
        float4 y1 = *(const float4*)(y + 4);
        float sum = y0.x + y0.y + y0.z + y0.w + y1.x + y1.y + y1.z + y1.w;
        float ssq = y0.x*y0.x + y0.y*y0.y + y0.z*y0.z + y0.w*y0.w
                  + y1.x*y1.x + y1.y*y1.y + y1.z*y1.z + y1.w*y1.w;
#pragma unroll
        for (int m = 1; m < 64; m <<= 1) {
            sum += __shfl_xor(sum, m, 64);
            ssq += __shfl_xor(ssq, m, 64);
        }
        float mean = sum * (1.0f / 512.0f);
        float var  = ssq * (1.0f / 512.0f) - mean * mean;
        float rstd = rsqrtf(var + 1e-5f);
        float4 g0 = *(const float4*)(g + c),  g1v = *(const float4*)(g + c + 4);
        float4 e0 = *(const float4*)(be + c), e1  = *(const float4*)(be + c + 4);
        float4 n0, n1;
        n0.x = (y0.x - mean) * rstd * g0.x  + e0.x;
        n0.y = (y0.y - mean) * rstd * g0.y  + e0.y;
        n0.z = (y0.z - mean) * rstd * g0.z  + e0.z;
        n0.w = (y0.w - mean) * rstd * g0.w  + e0.w;
        n1.x = (y1.x - mean) * rstd * g1v.x + e1.x;
        n1.y = (y1.y - mean) * rstd * g1v.y + e1.y;
        n1.z = (y1.z - mean) * rstd * g1v.z + e1.z;
        n1.w = (y1.w - mean) * rstd * g1v.w + e1.w;
        const int jm = row & 63;
        const float* bb = Bb + jm * D0 + c;
        float4 b0 = *(const float4*)bb, b1v = *(const float4*)(bb + 4);
        float p = n0.x*b0.x + n0.y*b0.y + n0.z*b0.z + n0.w*b0.w
                + n1.x*b1v.x + n1.y*b1v.y + n1.z*b1v.z + n1.w*b1v.w;
#pragma unroll
        for (int m = 1; m < 64; m <<= 1) p += __shfl_xor(p, m, 64);
        const float* av = AaT + jm * D0 + c;
        float4 a0 = *(const float4*)av, a1 = *(const float4*)(av + 4);
        const float* rs = RES + (size_t)row * ldr + c;
        float4 r0 = *(const float4*)rs, r1 = *(const float4*)(rs + 4);
        float4 v0, v1;
        v0.x = p*a0.x + r0.x; v0.y = p*a0.y + r0.y; v0.z = p*a0.z + r0.z; v0.w = p*a0.w + r0.w;
        v1.x = p*a1.x + r1.x; v1.y = p*a1.y + r1.y; v1.z = p*a1.z + r1.z; v1.w = p*a1.w + r1.w;
        if (outf) {
            *(float4*)(outf + (size_t)row * D0 + c)     = v0;
            *(float4*)(outf + (size_t)row * D0 + c + 4) = v1;
        } else {
            ushort4 h0, l0, h1, l1;
            hilo(v0.x, h0.x, l0.x); hilo(v0.y, h0.y, l0.y);
            hilo(v0.z, h0.z, l0.z); hilo(v0.w, h0.w, l0.w);
            hilo(v1.x, h1.x, l1.x); hilo(v1.y, h1.y, l1.y);
            hilo(v1.z, h1.z, l1.z); hilo(v1.w, h1.w, l1.w);
            *(ushort4*)(outh + (size_t)row * D0 + c)     = h0;
            *(ushort4*)(outl + (size_t)row * D0 + c)     = l0;
            *(ushort4*)(outh + (size_t)row * D0 + c + 4) = h1;
            *(ushort4*)(outl + (size_t)row * D0 + c + 4) = l1;
        }
    }
}

// ---------------------------------------------------------------------------
// TS stage for one sequence position s. C2 has 4 split-K partials of
// (4096 x 128): cols [0,64)=M2 path, [64,128)=R2 residual path.
// tsb: [0,128) t, [128,256) residual, [256,768) partials.
// ---------------------------------------------------------------------------
#define C2S 524288
__device__ __forceinline__ void ts_stage(
        const float* __restrict__ C2, const float* __restrict__ g2,
        const float* __restrict__ b2, const float* __restrict__ P,
        unsigned short* __restrict__ Hh, unsigned short* __restrict__ Hl,
        int s, float* tsb) {
    float* tsh  = tsb;
    float* rsh  = tsb + 128;
    float* part = tsb + 256;
    const int tid = threadIdx.x;
    if (tid < 128) {
        int b = tid >> 6, j = tid & 63;
        size_t bs = (size_t)(b * SEQ + s) * 128;
        float v  = C2[bs + j]      + C2[C2S + bs + j]
                 + C2[2*C2S + bs + j]  + C2[3*C2S + bs + j];
        float rv = C2[bs + 64 + j] + C2[C2S + bs + 64 + j]
                 + C2[2*C2S + bs + 64 + j] + C2[3*C2S + bs + 64 + j];
        rsh[b * 64 + j] = rv;
        float sum = v, ssq = v * v;
#pragma unroll
        for (int m = 1; m < 64; m <<= 1) {
            sum += __shfl_xor(sum, m, 64);
            ssq += __shfl_xor(ssq, m, 64);
        }
        float mean = sum * (1.0f / 64.0f);
        float var  = ssq * (1.0f / 64.0f) - mean * mean;
        float rstd = rsqrtf(var + 1e-5f);
        tsh[b * 64 + j] = (v - mean) * rstd * g2[j] + b2[j];
    }
    __syncthreads();

    const int i  = tid & 63;
    const int jg = tid >> 6;
    const float sf = (float)s;
    float a0 = 0.f, a1 = 0.f;
    for (int jj = 0; jj < 16; ++jj) {
        int j = (jg << 4) + jj;
        const float* pp = P + (i * 64 + j) * 8;
        float base = (float)(i * 512 + j * 8 + 2);
        float w = 0.f;
#pragma unroll
        for (int gg = 0; gg < 8; ++gg) {
            float pval = base + (float)gg;
            float invp = __builtin_amdgcn_rcpf(pval);
            float q    = floorf(sf * invp);
            float rem  = fmaf(-q, pval, sf);    // exact small integer
            float fr   = rem * invp;
            fr = fr - floorf(fr);
            float cc = __builtin_amdgcn_cosf(fr);
            w = fmaf(pp[gg], cc, w);
        }
        a0 = fmaf(w, tsh[j], a0);
        a1 = fmaf(w, tsh[64 + j], a1);
    }
    part[(jg * 2 + 0) * 64 + i] = a0;
    part[(jg * 2 + 1) * 64 + i] = a1;
    __syncthreads();

    if (tid < 128) {
        int b = tid >> 6, ii = tid & 63;
        float nk = part[(0*2+b)*64 + ii] + part[(1*2+b)*64 + ii]
                 + part[(2*2+b)*64 + ii] + part[(3*2+b)*64 + ii] + rsh[b * 64 + ii];
        size_t idx = (size_t)(b * SEQ + s) * D1 + ii;
        unsigned short h, lo_;
        hilo(nk, h, lo_);
        Hh[idx] = h; Hl[idx] = lo_;
    }
    __syncthreads();   // protect tsh/rsh/part for next s
}

// ---------------------------------------------------------------------------
// The cooperative mega-kernel: all 7 stages with grid-wide syncs.
// 256 blocks x 256 threads (1 block/CU).
// ---------------------------------------------------------------------------
__global__ __launch_bounds__(256) void megak(
        const float* __restrict__ x,  const float* __restrict__ W1,
        const float* __restrict__ g1, const float* __restrict__ b1,
        const float* __restrict__ A1, const float* __restrict__ B1,
        const float* __restrict__ M2, const float* __restrict__ g2,
        const float* __restrict__ b2, const float* __restrict__ P2,
        const float* __restrict__ R2, const float* __restrict__ W3,
        const float* __restrict__ g3, const float* __restrict__ b3,
        const float* __restrict__ A3, const float* __restrict__ B3,
        const float* __restrict__ R3, float* __restrict__ out,
        float* __restrict__ ws) {
    // workspace layout (floats)
    float* C1  = ws;                 // 2,097,152
    float* C2  = ws + 2097152;       // 2,097,152 (4 x 524288 split-K partials)
    float* C3  = ws + 4194304;       // 4,194,304
    float* A1T = ws + 8388608;       // 32,768  (64 x 512)
    float* A3T = ws + 8421376;       // 32,768
    unsigned short* us = (unsigned short*)(ws + 8454144);
    unsigned short* xh   = us;
    unsigned short* xl   = us + 2097152;
    unsigned short* h1h  = us + 4194304;
    unsigned short* h1l  = us + 6291456;
    unsigned short* W1h  = us + 8388608;   // 262,144
    unsigned short* W1l  = us + 8650752;
    unsigned short* Wc2h = us + 8912896;   // 65,536 (128 x 512)
    unsigned short* Wc2l = us + 8978432;
    unsigned short* Wc3h = us + 9043968;   // 65,536 (1024 x 64)
    unsigned short* Wc3l = us + 9109504;
    unsigned short* h2h  = us + 9175040;   // 262,144 (4096 x 64)
    unsigned short* h2l  = us + 9437184;

    __shared__ __align__(16) unsigned short aH[8192], aL[8192], wH[4096], wL[4096]; // 48 KB
    __shared__ float tsb[768];                                                      // 3 KB

    const int bid = blockIdx.x;
    const int tid = threadIdx.x;
    cg::grid_group grid = cg::this_grid();

    // ---- stage 0: convert inputs to bf16 hi/lo planes + transpose A1/A3 ----
    for (int r = 0; r < 5; ++r) {
        int c = bid + r * 256;
        if (c < 1216) {
            const float* src; unsigned short *dh, *dl; int off;
            if      (c < 1024) { src = x;  dh = xh;           dl = xl;           off = c; }
            else if (c < 1152) { src = W1; dh = W1h;          dl = W1l;          off = c - 1024; }
            else if (c < 1168) { src = M2; dh = Wc2h;         dl = Wc2l;         off = c - 1152; }
            else if (c < 1184) { src = R2; dh = Wc2h + 32768; dl = Wc2l + 32768; off = c - 1168; }
            else if (c < 1200) { src = W3; dh = Wc3h;         dl = Wc3l;         off = c - 1184; }
            else               { src = R3; dh = Wc3h + 32768; dl = Wc3l + 32768; off = c - 1200; }
            int base = off * 2048 + tid * 4;
            float4 v0 = *(const float4*)(src + base);
            float4 v1 = *(const float4*)(src + base + 1024);
            cv4(dh, dl, base, v0);
            cv4(dh, dl, base + 1024, v1);
        }
    }
    {
        int gid = bid * 256 + tid;
        if (gid < 32768) {
            int i = gid >> 6, j = gid & 63;
            A1T[j * 512 + i] = A1[gid];
            A3T[j * 512 + i] = A3[gid];
        }
    }
    __threadfence(); grid.sync();

    // ---- stage 1: C1 = x @ W1^T  (4096x512, K=512; 256 tiles) ----
    gemm_tile(xh, xl, W1h, W1l, C1, ROWS, 512, 512, 512, bid & 7, bid >> 3, 0,
              aH, aL, wH, wL);
    __threadfence(); grid.sync();

    // ---- stage 2: h1 = RN(C1) + x  -> bf16 planes ----
    lnrn_stage(C1, 512, x, 512, g1, b1, B1, A1T, nullptr, h1h, h1l);
    __threadfence(); grid.sync();

    // ---- stage 3: C2 = h1 @ [M2;R2]^T (4096x128, K=512, split-K=4; 256 tiles) ----
    gemm_tile(h1h, h1l, Wc2h, Wc2l, C2, ROWS, 128, 512, 128,
              bid & 1, (bid >> 1) & 31, bid >> 6, aH, aL, wH, wL);
    __threadfence(); grid.sync();

    // ---- stage 4: h2 = TS(C2) -> bf16 planes (8 positions per block) ----
    for (int r = 0; r < 8; ++r)
        ts_stage(C2, g2, b2, P2, h2h, h2l, bid + r * 256, tsb);
    __threadfence(); grid.sync();

    // ---- stage 5: C3 = h2 @ [W3;R3]^T (4096x1024, K=64; 512 tiles, 2/block) ----
    for (int r = 0; r < 2; ++r) {
        int t = bid + r * 256;
        gemm_tile(h2h, h2l, Wc3h, Wc3l, C3, ROWS, 1024, 64, 64,
                  t & 15, t >> 4, 0, aH, aL, wH, wL);
    }
    __threadfence(); grid.sync();

    // ---- stage 6: out = RN(C3[:, :512]) + C3[:, 512:]  (fp32) ----
    lnrn_stage(C3, 1024, C3 + 512, 1024, g3, b3, B3, A3T, out, nullptr, nullptr);
}

// ---------------------------------------------------------------------------
extern "C" void kernel_launch(void* const* d_in, const int* in_sizes, int n_in,
                              void* d_out, int out_size, void* d_ws, size_t ws_size,
                              hipStream_t stream) {
    const float* x  = (const float*)d_in[0];
    const float* W1 = (const float*)d_in[1];
    const float* g1 = (const float*)d_in[2];
    const float* b1 = (const float*)d_in[3];
    const float* A1 = (const float*)d_in[4];
    const float* B1 = (const float*)d_in[5];
    const float* M2 = (const float*)d_in[6];
    const float* g2 = (const float*)d_in[7];
    const float* b2 = (const float*)d_in[8];
    const float* P2 = (const float*)d_in[9];
    const float* R2 = (const float*)d_in[10];
    const float* W3 = (const float*)d_in[11];
    const float* g3 = (const float*)d_in[12];
    const float* b3 = (const float*)d_in[13];
    const float* A3 = (const float*)d_in[14];
    const float* B3 = (const float*)d_in[15];
    const float* R3 = (const float*)d_in[16];
    float* out = (float*)d_out;
    float* ws  = (float*)d_ws;

    void* args[] = { &x, &W1, &g1, &b1, &A1, &B1, &M2, &g2, &b2, &P2, &R2,
                     &W3, &g3, &b3, &A3, &B3, &R3, &out, &ws };
    hipLaunchCooperativeKernel((const void*)megak, dim3(256), dim3(256),
                               args, 0, stream);
}

// Round 4
// 167.694 us; speedup vs baseline: 3.3291x; 3.3291x over previous
//
#include <hip/hip_runtime.h>
#include <math.h>

#define SEQ  2048
#define ROWS 4096
#define D0   512
#define D1   64

typedef short bf8 __attribute__((ext_vector_type(8)));   // 8 bf16 = 4 VGPRs
typedef float f4  __attribute__((ext_vector_type(4)));   // MFMA acc

// fp32 -> bf16 hi/lo split (RNE)
__device__ __forceinline__ unsigned short f2bf(float f) {
    unsigned u = __float_as_uint(f);
    return (unsigned short)((u + 0x7fffu + ((u >> 16) & 1u)) >> 16);
}
__device__ __forceinline__ void hilo(float f, unsigned short& h, unsigned short& l) {
    h = f2bf(f);
    float fh = __uint_as_float((unsigned)h << 16);
    l = f2bf(f - fh);
}
__device__ __forceinline__ void cv4(unsigned short* dh, unsigned short* dl, int idx, float4 v) {
    ushort4 hv, lv;
    hilo(v.x, hv.x, lv.x); hilo(v.y, hv.y, lv.y);
    hilo(v.z, hv.z, lv.z); hilo(v.w, hv.w, lv.w);
    *(ushort4*)(dh + idx) = hv;
    *(ushort4*)(dl + idx) = lv;
}

// async global->LDS 16B (dest = wave-uniform base + lane*16)
__device__ __forceinline__ void async16(const void* g, void* l) {
    __builtin_amdgcn_global_load_lds(
        (const __attribute__((address_space(1))) unsigned int*)g,
        (__attribute__((address_space(3))) unsigned int*)l, 16, 0, 0);
}

// ---------------------------------------------------------------------------
// Conversion: fp32 -> bf16 hi/lo planes + A1/A3 transpose.
// Blocks [0,1216): conversions (2048 elems each). [1216,1344): transposes.
// ---------------------------------------------------------------------------
__global__ __launch_bounds__(256) void convk(
        const float* __restrict__ x,  const float* __restrict__ W1,
        const float* __restrict__ M2, const float* __restrict__ R2,
        const float* __restrict__ W3, const float* __restrict__ R3,
        const float* __restrict__ A1, const float* __restrict__ A3,
        unsigned short* __restrict__ xh,  unsigned short* __restrict__ xl,
        unsigned short* __restrict__ W1h, unsigned short* __restrict__ W1l,
        unsigned short* __restrict__ C2h, unsigned short* __restrict__ C2l,
        unsigned short* __restrict__ C3h, unsigned short* __restrict__ C3l,
        float* __restrict__ A1T, float* __restrict__ A3T) {
    int c = blockIdx.x, tid = threadIdx.x;
    if (c < 1216) {
        const float* src; unsigned short *dh, *dl; int off;
        if      (c < 1024) { src = x;  dh = xh;          dl = xl;          off = c; }
        else if (c < 1152) { src = W1; dh = W1h;         dl = W1l;         off = c - 1024; }
        else if (c < 1168) { src = M2; dh = C2h;         dl = C2l;         off = c - 1152; }
        else if (c < 1184) { src = R2; dh = C2h + 32768; dl = C2l + 32768; off = c - 1168; }
        else if (c < 1200) { src = W3; dh = C3h;         dl = C3l;         off = c - 1184; }
        else               { src = R3; dh = C3h + 32768; dl = C3l + 32768; off = c - 1200; }
        int base = off * 2048 + tid * 4;
        cv4(dh, dl, base,        *(const float4*)(src + base));
        cv4(dh, dl, base + 1024, *(const float4*)(src + base + 1024));
    } else {
        int gid = (c - 1216) * 256 + tid;     // 0..32767
        int i = gid >> 6, j = gid & 63;       // A (512 x 64)
        A1T[j * 512 + i] = A1[gid];
        A3T[j * 512 + i] = A3[gid];
    }
}

// ---------------------------------------------------------------------------
// bf16x3 MFMA GEMM, 64x64 tile, BK=64, 256 thr (4 waves; wave wv -> rows
// [wv*16,+16)). XOR-swizzled LDS: chunk ch of row r stored at slot ch^(r&7),
// applied on the GLOBAL source index so global_load_lds dest stays
// wave-uniform base + lane*16B. Fragment reads then hit 32 banks, 2 lanes ea.
// grid: x = N/64, y = M/64, z = split-K (k0 = z*Ks, C += z*M*N).
// ---------------------------------------------------------------------------
__global__ __launch_bounds__(256, 4) void gemm64(
        const unsigned short* __restrict__ Ah, const unsigned short* __restrict__ Al,
        const unsigned short* __restrict__ Wh, const unsigned short* __restrict__ Wl,
        float* __restrict__ C, int M, int N, int K, int Ks) {
    __shared__ __align__(16) unsigned short aH[4096], aL[4096], wH[4096], wL[4096];
    const int tid = threadIdx.x;
    const int wv  = tid >> 6;
    const int ln  = tid & 63;
    const int lm  = ln & 15;
    const int lq  = ln >> 4;
    const int bm  = blockIdx.y * 64;
    const int bn  = blockIdx.x * 64;
    const int k0  = blockIdx.z * Ks;
    C += (size_t)blockIdx.z * M * N;

    f4 acc[4] = {};

    for (int kt = 0; kt < Ks; kt += 64) {
        const int kg = k0 + kt;
        __syncthreads();
#pragma unroll
        for (int i = 0; i < 2; ++i) {
            int slot = i * 256 + wv * 64 + ln;   // 0..511 ; lds addr = slot*16B
            int row  = slot >> 3;
            int ch   = (slot & 7) ^ (row & 7);   // swizzle on global side
            size_t goA = (size_t)(bm + row) * K + kg + ch * 8;
            size_t goW = (size_t)(bn + row) * K + kg + ch * 8;
            async16(Ah + goA, aH + slot * 8);
            async16(Al + goA, aL + slot * 8);
            async16(Wh + goW, wH + slot * 8);
            async16(Wl + goW, wL + slot * 8);
        }
        __syncthreads();

#pragma unroll
        for (int kk = 0; kk < 2; ++kk) {
            const int ck = kk * 4 + lq;          // 16B chunk index in k
            const int r  = wv * 16 + lm;
            bf8 ah = *(const bf8*)(aH + r * 64 + ((ck ^ (r & 7)) * 8));
            bf8 al = *(const bf8*)(aL + r * 64 + ((ck ^ (r & 7)) * 8));
            bf8 bh[4], bl[4];
#pragma unroll
            for (int u = 0; u < 4; ++u) {
                int rb = u * 16 + lm;
                bh[u] = *(const bf8*)(wH + rb * 64 + ((ck ^ (rb & 7)) * 8));
                bl[u] = *(const bf8*)(wL + rb * 64 + ((ck ^ (rb & 7)) * 8));
            }
#pragma unroll
            for (int u = 0; u < 4; ++u) {
                acc[u] = __builtin_amdgcn_mfma_f32_16x16x32_bf16(ah, bh[u], acc[u], 0, 0, 0);
                acc[u] = __builtin_amdgcn_mfma_f32_16x16x32_bf16(ah, bl[u], acc[u], 0, 0, 0);
                acc[u] = __builtin_amdgcn_mfma_f32_16x16x32_bf16(al, bh[u], acc[u], 0, 0, 0);
            }
        }
    }

    // C/D layout (verified): col = lane&15, row = quad*4 + reg
#pragma unroll
    for (int u = 0; u < 4; ++u) {
        int row = bm + wv * 16 + lq * 4;
        int col = bn + u * 16 + lm;
#pragma unroll
        for (int r = 0; r < 4; ++r)
            C[(size_t)(row + r) * N + col] = acc[u][r];
    }
}

// ---------------------------------------------------------------------------
// LN + rank-1 RN epilogue, one row per wave (1024 blocks x 4 waves = 4096).
// Y2 (optional) = second split-K partial to sum. Output fp32 or bf16 planes.
// ---------------------------------------------------------------------------
__global__ __launch_bounds__(256) void lnrn(
        const float* __restrict__ Y, const float* __restrict__ Y2, int ldy,
        const float* __restrict__ RES, int ldr,
        const float* __restrict__ g, const float* __restrict__ be,
        const float* __restrict__ Bb, const float* __restrict__ AaT,
        float* __restrict__ outf,
        unsigned short* __restrict__ outh, unsigned short* __restrict__ outl) {
    const int row = blockIdx.x * 4 + (threadIdx.x >> 6);
    const int l = threadIdx.x & 63;
    const int c = l * 8;
    const float* y = Y + (size_t)row * ldy + c;
    float4 y0 = *(const float4*)y;
    float4 y1 = *(const float4*)(y + 4);
    if (Y2) {
        const float* y2 = Y2 + (size_t)row * ldy + c;
        float4 p0 = *(const float4*)y2, p1 = *(const float4*)(y2 + 4);
        y0.x += p0.x; y0.y += p0.y; y0.z += p0.z; y0.w += p0.w;
        y1.x += p1.x; y1.y += p1.y; y1.z += p1.z; y1.w += p1.w;
    }
    float sum = y0.x + y0.y + y0.z + y0.w + y1.x + y1.y + y1.z + y1.w;
    float ssq = y0.x*y0.x + y0.y*y0.y + y0.z*y0.z + y0.w*y0.w
              + y1.x*y1.x + y1.y*y1.y + y1.z*y1.z + y1.w*y1.w;
#pragma unroll
    for (int m = 1; m < 64; m <<= 1) {
        sum += __shfl_xor(sum, m, 64);
        ssq += __shfl_xor(ssq, m, 64);
    }
    float mean = sum * (1.0f / 512.0f);
    float var  = ssq * (1.0f / 512.0f) - mean * mean;
    float rstd = rsqrtf(var + 1e-5f);
    float4 g0 = *(const float4*)(g + c),  g1v = *(const float4*)(g + c + 4);
    float4 e0 = *(const float4*)(be + c), e1  = *(const float4*)(be + c + 4);
    float4 n0, n1;
    n0.x = (y0.x - mean) * rstd * g0.x  + e0.x;
    n0.y = (y0.y - mean) * rstd * g0.y  + e0.y;
    n0.z = (y0.z - mean) * rstd * g0.z  + e0.z;
    n0.w = (y0.w - mean) * rstd * g0.w  + e0.w;
    n1.x = (y1.x - mean) * rstd * g1v.x + e1.x;
    n1.y = (y1.y - mean) * rstd * g1v.y + e1.y;
    n1.z = (y1.z - mean) * rstd * g1v.z + e1.z;
    n1.w = (y1.w - mean) * rstd * g1v.w + e1.w;
    const int jm = row & 63;
    const float* bb = Bb + jm * D0 + c;
    float4 b0 = *(const float4*)bb, b1v = *(const float4*)(bb + 4);
    float p = n0.x*b0.x + n0.y*b0.y + n0.z*b0.z + n0.w*b0.w
            + n1.x*b1v.x + n1.y*b1v.y + n1.z*b1v.z + n1.w*b1v.w;
#pragma unroll
    for (int m = 1; m < 64; m <<= 1) p += __shfl_xor(p, m, 64);
    const float* av = AaT + jm * D0 + c;
    float4 a0 = *(const float4*)av, a1 = *(const float4*)(av + 4);
    const float* rs = RES + (size_t)row * ldr + c;
    float4 r0 = *(const float4*)rs, r1 = *(const float4*)(rs + 4);
    float4 v0, v1;
    v0.x = p*a0.x + r0.x; v0.y = p*a0.y + r0.y; v0.z = p*a0.z + r0.z; v0.w = p*a0.w + r0.w;
    v1.x = p*a1.x + r1.x; v1.y = p*a1.y + r1.y; v1.z = p*a1.z + r1.z; v1.w = p*a1.w + r1.w;
    if (outf) {
        *(float4*)(outf + (size_t)row * D0 + c)     = v0;
        *(float4*)(outf + (size_t)row * D0 + c + 4) = v1;
    } else {
        ushort4 h0, l0, h1, l1;
        hilo(v0.x, h0.x, l0.x); hilo(v0.y, h0.y, l0.y);
        hilo(v0.z, h0.z, l0.z); hilo(v0.w, h0.w, l0.w);
        hilo(v1.x, h1.x, l1.x); hilo(v1.y, h1.y, l1.y);
        hilo(v1.z, h1.z, l1.z); hilo(v1.w, h1.w, l1.w);
        *(ushort4*)(outh + (size_t)row * D0 + c)     = h0;
        *(ushort4*)(outl + (size_t)row * D0 + c)     = l0;
        *(ushort4*)(outh + (size_t)row * D0 + c + 4) = h1;
        *(ushort4*)(outl + (size_t)row * D0 + c + 4) = l1;
    }
}

// ---------------------------------------------------------------------------
// TS layer. C2 = 8 split-K partials, each (4096 x 128): cols [0,64)=M2 path,
// [64,128)=R2 residual. One block per s. Output bf16 hi/lo planes of h2.
// ---------------------------------------------------------------------------
#define C2S 524288
__global__ __launch_bounds__(256, 8) void tsk(
        const float* __restrict__ C2, const float* __restrict__ g2,
        const float* __restrict__ b2, const float* __restrict__ P,
        unsigned short* __restrict__ Hh, unsigned short* __restrict__ Hl) {
    __shared__ float tsh[2][64];
    __shared__ float rsh[2][64];
    __shared__ float part[4][2][64];
    const int s = blockIdx.x;
    const int tid = threadIdx.x;

    if (tid < 128) {
        int b = tid >> 6, j = tid & 63;
        size_t bs = (size_t)(b * SEQ + s) * 128;
        float v = 0.f, rv = 0.f;
#pragma unroll
        for (int z = 0; z < 8; ++z) {
            v  += C2[(size_t)z * C2S + bs + j];
            rv += C2[(size_t)z * C2S + bs + 64 + j];
        }
        rsh[b][j] = rv;
        float sum = v, ssq = v * v;
#pragma unroll
        for (int m = 1; m < 64; m <<= 1) {
            sum += __shfl_xor(sum, m, 64);
            ssq += __shfl_xor(ssq, m, 64);
        }
        float mean = sum * (1.0f / 64.0f);
        float var  = ssq * (1.0f / 64.0f) - mean * mean;
        float rstd = rsqrtf(var + 1e-5f);
        tsh[b][j] = (v - mean) * rstd * g2[j] + b2[j];
    }
    __syncthreads();

    const int i  = tid & 63;
    const int jg = tid >> 6;
    const float sf = (float)s;
    float a0 = 0.f, a1 = 0.f;
    for (int jj = 0; jj < 16; ++jj) {
        int j = (jg << 4) + jj;
        const float* pp = P + (i * 64 + j) * 8;
        float base = (float)(i * 512 + j * 8 + 2);
        float w = 0.f;
#pragma unroll
        for (int gg = 0; gg < 8; ++gg) {
            float pval = base + (float)gg;
            float invp = __builtin_amdgcn_rcpf(pval);
            float q    = floorf(sf * invp);
            float rem  = fmaf(-q, pval, sf);    // exact small integer
            float fr   = rem * invp;
            fr = fr - floorf(fr);
            float cc = __builtin_amdgcn_cosf(fr); // cos(2*pi*fr)
            w = fmaf(pp[gg], cc, w);
        }
        a0 = fmaf(w, tsh[0][j], a0);
        a1 = fmaf(w, tsh[1][j], a1);
    }
    part[jg][0][i] = a0;
    part[jg][1][i] = a1;
    __syncthreads();

    if (tid < 128) {
        int b = tid >> 6, ii = tid & 63;
        float nk = part[0][b][ii] + part[1][b][ii] + part[2][b][ii] + part[3][b][ii]
                 + rsh[b][ii];
        size_t idx = (size_t)(b * SEQ + s) * D1 + ii;
        unsigned short h, lo_;
        hilo(nk, h, lo_);
        Hh[idx] = h; Hl[idx] = lo_;
    }
}

// ---------------------------------------------------------------------------
extern "C" void kernel_launch(void* const* d_in, const int* in_sizes, int n_in,
                              void* d_out, int out_size, void* d_ws, size_t ws_size,
                              hipStream_t stream) {
    const float* x  = (const float*)d_in[0];
    const float* W1 = (const float*)d_in[1];
    const float* g1 = (const float*)d_in[2];
    const float* b1 = (const float*)d_in[3];
    const float* A1 = (const float*)d_in[4];
    const float* B1 = (const float*)d_in[5];
    const float* M2 = (const float*)d_in[6];
    const float* g2 = (const float*)d_in[7];
    const float* b2 = (const float*)d_in[8];
    const float* P2 = (const float*)d_in[9];
    const float* R2 = (const float*)d_in[10];
    const float* W3 = (const float*)d_in[11];
    const float* g3 = (const float*)d_in[12];
    const float* b3 = (const float*)d_in[13];
    const float* A3 = (const float*)d_in[14];
    const float* B3 = (const float*)d_in[15];
    const float* R3 = (const float*)d_in[16];

    float* ws = (float*)d_ws;
    float* C1  = ws;                   // 2 partials x 2,097,152 = 4,194,304
    float* C2  = ws + 4194304;         // 8 partials x 524,288   = 4,194,304
    float* C3  = ws + 8388608;         // 4,194,304
    float* A1T = ws + 12582912;        // 32,768 (64 x 512)
    float* A3T = ws + 12615680;        // 32,768
    unsigned short* us = (unsigned short*)(ws + 12648448);
    unsigned short* xh   = us;                  // 2,097,152 each
    unsigned short* xl   = us + 2097152;
    unsigned short* h1h  = us + 4194304;
    unsigned short* h1l  = us + 6291456;
    unsigned short* W1h  = us + 8388608;        // 262,144 each
    unsigned short* W1l  = us + 8650752;
    unsigned short* Wc2h = us + 8912896;        // 65,536 each (128 x 512)
    unsigned short* Wc2l = us + 8978432;
    unsigned short* Wc3h = us + 9043968;        // 65,536 each (1024 x 64)
    unsigned short* Wc3l = us + 9109504;
    unsigned short* h2h  = us + 9175040;        // 262,144 each (4096 x 64)
    unsigned short* h2l  = us + 9437184;

    dim3 blk(256);

    // 0) convert + transpose
    convk<<<1344, blk, 0, stream>>>(x, W1, M2, R2, W3, R3, A1, A3,
                                    xh, xl, W1h, W1l, Wc2h, Wc2l, Wc3h, Wc3l,
                                    A1T, A3T);

    // 1) C1 = x @ W1^T (4096x512, K=512, split-K=2 -> 1024 blocks)
    gemm64<<<dim3(8, 64, 2), blk, 0, stream>>>(xh, xl, W1h, W1l, C1, ROWS, 512, 512, 256);
    //    h1 = RN(C1p0+C1p1) + x -> bf16 planes
    lnrn<<<1024, blk, 0, stream>>>(C1, C1 + 2097152, 512, x, 512, g1, b1, B1, A1T,
                                   nullptr, h1h, h1l);

    // 2) C2 = h1 @ [M2;R2]^T (4096x128, K=512, split-K=8 -> 1024 blocks)
    gemm64<<<dim3(2, 64, 8), blk, 0, stream>>>(h1h, h1l, Wc2h, Wc2l, C2, ROWS, 128, 512, 64);
    //    h2 = TS(C2) -> bf16 planes
    tsk<<<SEQ, blk, 0, stream>>>(C2, g2, b2, P2, h2h, h2l);

    // 3) C3 = h2 @ [W3;R3]^T (4096x1024, K=64 -> 1024 blocks)
    gemm64<<<dim3(16, 64, 1), blk, 0, stream>>>(h2h, h2l, Wc3h, Wc3l, C3, ROWS, 1024, 64, 64);
    //    out = RN(C3[:, :512]) + C3[:, 512:]
    lnrn<<<1024, blk, 0, stream>>>(C3, nullptr, 1024, C3 + 512, 1024, g3, b3, B3, A3T,
                                   (float*)d_out, nullptr, nullptr);
}

// Round 5
// 159.120 us; speedup vs baseline: 3.5085x; 1.0539x over previous
//
#include <hip/hip_runtime.h>
#include <math.h>

#define SEQ  2048
#define ROWS 4096
#define D0   512
#define D1   64

typedef short bf8 __attribute__((ext_vector_type(8)));   // 8 bf16 = 4 VGPRs
typedef float f4  __attribute__((ext_vector_type(4)));   // MFMA acc

// fp32 -> bf16 hi/lo split (RNE)
__device__ __forceinline__ unsigned short f2bf(float f) {
    unsigned u = __float_as_uint(f);
    return (unsigned short)((u + 0x7fffu + ((u >> 16) & 1u)) >> 16);
}
__device__ __forceinline__ void hilo(float f, unsigned short& h, unsigned short& l) {
    h = f2bf(f);
    float fh = __uint_as_float((unsigned)h << 16);
    l = f2bf(f - fh);
}
__device__ __forceinline__ void cv4(unsigned short* dh, unsigned short* dl, int idx, float4 v) {
    ushort4 hv, lv;
    hilo(v.x, hv.x, lv.x); hilo(v.y, hv.y, lv.y);
    hilo(v.z, hv.z, lv.z); hilo(v.w, hv.w, lv.w);
    *(ushort4*)(dh + idx) = hv;
    *(ushort4*)(dl + idx) = lv;
}

// async global->LDS 16B (dest = wave-uniform base + lane*16)
__device__ __forceinline__ void async16(const void* g, void* l) {
    __builtin_amdgcn_global_load_lds(
        (const __attribute__((address_space(1))) unsigned int*)g,
        (__attribute__((address_space(3))) unsigned int*)l, 16, 0, 0);
}

// ---------------------------------------------------------------------------
// Conversion: fp32 -> bf16 hi/lo planes + A1/A3 transpose.
// ---------------------------------------------------------------------------
__global__ __launch_bounds__(256) void convk(
        const float* __restrict__ x,  const float* __restrict__ W1,
        const float* __restrict__ M2, const float* __restrict__ R2,
        const float* __restrict__ W3, const float* __restrict__ R3,
        const float* __restrict__ A1, const float* __restrict__ A3,
        unsigned short* __restrict__ xh,  unsigned short* __restrict__ xl,
        unsigned short* __restrict__ W1h, unsigned short* __restrict__ W1l,
        unsigned short* __restrict__ C2h, unsigned short* __restrict__ C2l,
        unsigned short* __restrict__ C3h, unsigned short* __restrict__ C3l,
        float* __restrict__ A1T, float* __restrict__ A3T) {
    int c = blockIdx.x, tid = threadIdx.x;
    if (c < 1216) {
        const float* src; unsigned short *dh, *dl; int off;
        if      (c < 1024) { src = x;  dh = xh;          dl = xl;          off = c; }
        else if (c < 1152) { src = W1; dh = W1h;         dl = W1l;         off = c - 1024; }
        else if (c < 1168) { src = M2; dh = C2h;         dl = C2l;         off = c - 1152; }
        else if (c < 1184) { src = R2; dh = C2h + 32768; dl = C2l + 32768; off = c - 1168; }
        else if (c < 1200) { src = W3; dh = C3h;         dl = C3l;         off = c - 1184; }
        else               { src = R3; dh = C3h + 32768; dl = C3l + 32768; off = c - 1200; }
        int base = off * 2048 + tid * 4;
        cv4(dh, dl, base,        *(const float4*)(src + base));
        cv4(dh, dl, base + 1024, *(const float4*)(src + base + 1024));
    } else {
        int gid = (c - 1216) * 256 + tid;     // 0..32767
        int i = gid >> 6, j = gid & 63;       // A (512 x 64)
        A1T[j * 512 + i] = A1[gid];
        A3T[j * 512 + i] = A3[gid];
    }
}

// ---------------------------------------------------------------------------
// bf16x3 MFMA GEMM, 64x64 tile, BK=64, XOR-swizzled LDS (as R4, passed).
// ---------------------------------------------------------------------------
__global__ __launch_bounds__(256, 4) void gemm64(
        const unsigned short* __restrict__ Ah, const unsigned short* __restrict__ Al,
        const unsigned short* __restrict__ Wh, const unsigned short* __restrict__ Wl,
        float* __restrict__ C, int M, int N, int K, int Ks) {
    __shared__ __align__(16) unsigned short aH[4096], aL[4096], wH[4096], wL[4096];
    const int tid = threadIdx.x;
    const int wv  = tid >> 6;
    const int ln  = tid & 63;
    const int lm  = ln & 15;
    const int lq  = ln >> 4;
    const int bm  = blockIdx.y * 64;
    const int bn  = blockIdx.x * 64;
    const int k0  = blockIdx.z * Ks;
    C += (size_t)blockIdx.z * M * N;

    f4 acc[4] = {};

    for (int kt = 0; kt < Ks; kt += 64) {
        const int kg = k0 + kt;
        __syncthreads();
#pragma unroll
        for (int i = 0; i < 2; ++i) {
            int slot = i * 256 + wv * 64 + ln;   // 0..511 ; lds addr = slot*16B
            int row  = slot >> 3;
            int ch   = (slot & 7) ^ (row & 7);   // swizzle on global side
            size_t goA = (size_t)(bm + row) * K + kg + ch * 8;
            size_t goW = (size_t)(bn + row) * K + kg + ch * 8;
            async16(Ah + goA, aH + slot * 8);
            async16(Al + goA, aL + slot * 8);
            async16(Wh + goW, wH + slot * 8);
            async16(Wl + goW, wL + slot * 8);
        }
        __syncthreads();

#pragma unroll
        for (int kk = 0; kk < 2; ++kk) {
            const int ck = kk * 4 + lq;          // 16B chunk index in k
            const int r  = wv * 16 + lm;
            bf8 ah = *(const bf8*)(aH + r * 64 + ((ck ^ (r & 7)) * 8));
            bf8 al = *(const bf8*)(aL + r * 64 + ((ck ^ (r & 7)) * 8));
            bf8 bh[4], bl[4];
#pragma unroll
            for (int u = 0; u < 4; ++u) {
                int rb = u * 16 + lm;
                bh[u] = *(const bf8*)(wH + rb * 64 + ((ck ^ (rb & 7)) * 8));
                bl[u] = *(const bf8*)(wL + rb * 64 + ((ck ^ (rb & 7)) * 8));
            }
#pragma unroll
            for (int u = 0; u < 4; ++u) {
                acc[u] = __builtin_amdgcn_mfma_f32_16x16x32_bf16(ah, bh[u], acc[u], 0, 0, 0);
                acc[u] = __builtin_amdgcn_mfma_f32_16x16x32_bf16(ah, bl[u], acc[u], 0, 0, 0);
                acc[u] = __builtin_amdgcn_mfma_f32_16x16x32_bf16(al, bh[u], acc[u], 0, 0, 0);
            }
        }
    }

    // C/D layout (verified): col = lane&15, row = quad*4 + reg
#pragma unroll
    for (int u = 0; u < 4; ++u) {
        int row = bm + wv * 16 + lq * 4;
        int col = bn + u * 16 + lm;
#pragma unroll
        for (int r = 0; r < 4; ++r)
            C[(size_t)(row + r) * N + col] = acc[u][r];
    }
}

// ---------------------------------------------------------------------------
// LN + rank-1 RN epilogue, one row per wave (as R4, passed).
// ---------------------------------------------------------------------------
__global__ __launch_bounds__(256) void lnrn(
        const float* __restrict__ Y, const float* __restrict__ Y2, int ldy,
        const float* __restrict__ RES, int ldr,
        const float* __restrict__ g, const float* __restrict__ be,
        const float* __restrict__ Bb, const float* __restrict__ AaT,
        float* __restrict__ outf,
        unsigned short* __restrict__ outh, unsigned short* __restrict__ outl) {
    const int row = blockIdx.x * 4 + (threadIdx.x >> 6);
    const int l = threadIdx.x & 63;
    const int c = l * 8;
    const float* y = Y + (size_t)row * ldy + c;
    float4 y0 = *(const float4*)y;
    float4 y1 = *(const float4*)(y + 4);
    if (Y2) {
        const float* y2 = Y2 + (size_t)row * ldy + c;
        float4 p0 = *(const float4*)y2, p1 = *(const float4*)(y2 + 4);
        y0.x += p0.x; y0.y += p0.y; y0.z += p0.z; y0.w += p0.w;
        y1.x += p1.x; y1.y += p1.y; y1.z += p1.z; y1.w += p1.w;
    }
    float sum = y0.x + y0.y + y0.z + y0.w + y1.x + y1.y + y1.z + y1.w;
    float ssq = y0.x*y0.x + y0.y*y0.y + y0.z*y0.z + y0.w*y0.w
              + y1.x*y1.x + y1.y*y1.y + y1.z*y1.z + y1.w*y1.w;
#pragma unroll
    for (int m = 1; m < 64; m <<= 1) {
        sum += __shfl_xor(sum, m, 64);
        ssq += __shfl_xor(ssq, m, 64);
    }
    float mean = sum * (1.0f / 512.0f);
    float var  = ssq * (1.0f / 512.0f) - mean * mean;
    float rstd = rsqrtf(var + 1e-5f);
    float4 g0 = *(const float4*)(g + c),  g1v = *(const float4*)(g + c + 4);
    float4 e0 = *(const float4*)(be + c), e1  = *(const float4*)(be + c + 4);
    float4 n0, n1;
    n0.x = (y0.x - mean) * rstd * g0.x  + e0.x;
    n0.y = (y0.y - mean) * rstd * g0.y  + e0.y;
    n0.z = (y0.z - mean) * rstd * g0.z  + e0.z;
    n0.w = (y0.w - mean) * rstd * g0.w  + e0.w;
    n1.x = (y1.x - mean) * rstd * g1v.x + e1.x;
    n1.y = (y1.y - mean) * rstd * g1v.y + e1.y;
    n1.z = (y1.z - mean) * rstd * g1v.z + e1.z;
    n1.w = (y1.w - mean) * rstd * g1v.w + e1.w;
    const int jm = row & 63;
    const float* bb = Bb + jm * D0 + c;
    float4 b0 = *(const float4*)bb, b1v = *(const float4*)(bb + 4);
    float p = n0.x*b0.x + n0.y*b0.y + n0.z*b0.z + n0.w*b0.w
            + n1.x*b1v.x + n1.y*b1v.y + n1.z*b1v.z + n1.w*b1v.w;
#pragma unroll
    for (int m = 1; m < 64; m <<= 1) p += __shfl_xor(p, m, 64);
    const float* av = AaT + jm * D0 + c;
    float4 a0 = *(const float4*)av, a1 = *(const float4*)(av + 4);
    const float* rs = RES + (size_t)row * ldr + c;
    float4 r0 = *(const float4*)rs, r1 = *(const float4*)(rs + 4);
    float4 v0, v1;
    v0.x = p*a0.x + r0.x; v0.y = p*a0.y + r0.y; v0.z = p*a0.z + r0.z; v0.w = p*a0.w + r0.w;
    v1.x = p*a1.x + r1.x; v1.y = p*a1.y + r1.y; v1.z = p*a1.z + r1.z; v1.w = p*a1.w + r1.w;
    if (outf) {
        *(float4*)(outf + (size_t)row * D0 + c)     = v0;
        *(float4*)(outf + (size_t)row * D0 + c + 4) = v1;
    } else {
        ushort4 h0, l0, h1, l1;
        hilo(v0.x, h0.x, l0.x); hilo(v0.y, h0.y, l0.y);
        hilo(v0.z, h0.z, l0.z); hilo(v0.w, h0.w, l0.w);
        hilo(v1.x, h1.x, l1.x); hilo(v1.y, h1.y, l1.y);
        hilo(v1.z, h1.z, l1.z); hilo(v1.w, h1.w, l1.w);
        *(ushort4*)(outh + (size_t)row * D0 + c)     = h0;
        *(ushort4*)(outl + (size_t)row * D0 + c)     = l0;
        *(ushort4*)(outh + (size_t)row * D0 + c + 4) = h1;
        *(ushort4*)(outl + (size_t)row * D0 + c + 4) = l1;
    }
}

// ---------------------------------------------------------------------------
// lnt: sum 4 split-K partials of C2, LN the y-half -> t, sum residual -> rsum.
// One wave per row bs (1024 blocks x 4 waves). lane = j.
// ---------------------------------------------------------------------------
#define C2S 524288
__global__ __launch_bounds__(256) void lnt(
        const float* __restrict__ C2, const float* __restrict__ g2,
        const float* __restrict__ b2,
        float* __restrict__ t, float* __restrict__ rsum) {
    const int r = blockIdx.x * 4 + (threadIdx.x >> 6);   // 0..4095
    const int j = threadIdx.x & 63;
    size_t base = (size_t)r * 128 + j;
    float v = 0.f, rv = 0.f;
#pragma unroll
    for (int z = 0; z < 4; ++z) {
        v  += C2[(size_t)z * C2S + base];
        rv += C2[(size_t)z * C2S + base + 64];
    }
    float sum = v, ssq = v * v;
#pragma unroll
    for (int m = 1; m < 64; m <<= 1) {
        sum += __shfl_xor(sum, m, 64);
        ssq += __shfl_xor(ssq, m, 64);
    }
    float mean = sum * (1.0f / 64.0f);
    float var  = ssq * (1.0f / 64.0f) - mean * mean;
    float rstd = rsqrtf(var + 1e-5f);
    t[r * 64 + j]    = (v - mean) * rstd * g2[j] + b2[j];
    rsum[r * 64 + j] = rv;
}

// ---------------------------------------------------------------------------
// tsk2: Chebyshev-recurrence TS layer.
// grid 512 = i(64) x sg(8); wave w covers s in [sg*256+w*64, +64); lane = j.
// Each lane carries 8 g-chains: c_s = P[i,j,g]*cos(2*pi*s/p), advanced by
// c_{s+1} = 2cos(theta)*c_s - c_{s-1} (64-step chains, direct-eval anchored).
// Per s: w_j = sum_g c; butterfly-reduce sum_j w_j * t[b,s,j]; lane s keeps it.
// Epilogue: + rsum, -> bf16 hi/lo planes of h2.
// ---------------------------------------------------------------------------
__global__ __launch_bounds__(256) void tsk2(
        const float* __restrict__ t, const float* __restrict__ rsum,
        const float* __restrict__ P,
        unsigned short* __restrict__ Hh, unsigned short* __restrict__ Hl) {
    const int bid = blockIdx.x;
    const int i   = bid >> 3;
    const int sg  = bid & 7;
    const int w   = threadIdx.x >> 6;
    const int ln  = threadIdx.x & 63;       // j
    const int s0  = sg * 256 + w * 64;
    const int idx = i * 64 + ln;
    const float* pp = P + idx * 8;
    const float sf0 = (float)s0;

    float k2c[8], ca[8], cb[8];
#pragma unroll
    for (int g = 0; g < 8; ++g) {
        float pf   = (float)(idx * 8 + g + 2);
        float invp = __builtin_amdgcn_rcpf(pf);
        k2c[g] = 2.0f * __builtin_amdgcn_cosf(invp);     // 2*cos(2*pi/p)
        float q0 = floorf(sf0 * invp);
        float r0 = fmaf(-q0, pf, sf0);
        float f0 = r0 * invp; f0 -= floorf(f0);
        float c0 = __builtin_amdgcn_cosf(f0);            // cos(2*pi*s0/p)
        float sf1 = sf0 + 1.0f;
        float q1 = floorf(sf1 * invp);
        float r1 = fmaf(-q1, pf, sf1);
        float f1 = r1 * invp; f1 -= floorf(f1);
        float c1 = __builtin_amdgcn_cosf(f1);            // cos(2*pi*(s0+1)/p)
        float Pv = pp[g];
        ca[g] = Pv * c0;                                 // value at s0+even
        cb[g] = Pv * c1;                                 // value at s0+odd
    }

    const int tb = s0 * 64 + ln;                         // t[b=0][s0][j=ln]
    float t0c = t[tb], t1c = t[131072 + tb];             // 131072 = 2048*64
    float res0 = 0.f, res1 = 0.f;

    for (int st = 0; st < 64; st += 2) {
        // prefetch t for st+1 and st+2 (one-row overrun lands in rsum: safe)
        float t0n  = t[tb + (st + 1) * 64];
        float t1n  = t[131072 + tb + (st + 1) * 64];
        // ---- even step: value = ca ----
        float ws = ((ca[0] + ca[1]) + (ca[2] + ca[3]))
                 + ((ca[4] + ca[5]) + (ca[6] + ca[7]));
#pragma unroll
        for (int g = 0; g < 8; ++g) ca[g] = fmaf(k2c[g], cb[g], -ca[g]);
        float v0 = ws * t0c, v1 = ws * t1c;
#pragma unroll
        for (int m = 1; m < 64; m <<= 1) {
            v0 += __shfl_xor(v0, m, 64);
            v1 += __shfl_xor(v1, m, 64);
        }
        res0 = (ln == st) ? v0 : res0;
        res1 = (ln == st) ? v1 : res1;
        // ---- odd step: value = cb ----
        float t0n2 = t[tb + (st + 2) * 64];
        float t1n2 = t[131072 + tb + (st + 2) * 64];
        float ws2 = ((cb[0] + cb[1]) + (cb[2] + cb[3]))
                  + ((cb[4] + cb[5]) + (cb[6] + cb[7]));
#pragma unroll
        for (int g = 0; g < 8; ++g) cb[g] = fmaf(k2c[g], ca[g], -cb[g]);
        float v0b = ws2 * t0n, v1b = ws2 * t1n;
#pragma unroll
        for (int m = 1; m < 64; m <<= 1) {
            v0b += __shfl_xor(v0b, m, 64);
            v1b += __shfl_xor(v1b, m, 64);
        }
        res0 = (ln == st + 1) ? v0b : res0;
        res1 = (ln == st + 1) ? v1b : res1;
        t0c = t0n2; t1c = t1n2;
    }

    // lane ln holds Nk for s = s0 + ln
    const int s = s0 + ln;
    {
        float v = res0 + rsum[(size_t)s * 64 + i];
        unsigned short h, l; hilo(v, h, l);
        Hh[(size_t)s * 64 + i] = h; Hl[(size_t)s * 64 + i] = l;
        float v1e = res1 + rsum[(size_t)(SEQ + s) * 64 + i];
        hilo(v1e, h, l);
        Hh[(size_t)(SEQ + s) * 64 + i] = h; Hl[(size_t)(SEQ + s) * 64 + i] = l;
    }
}

// ---------------------------------------------------------------------------
extern "C" void kernel_launch(void* const* d_in, const int* in_sizes, int n_in,
                              void* d_out, int out_size, void* d_ws, size_t ws_size,
                              hipStream_t stream) {
    const float* x  = (const float*)d_in[0];
    const float* W1 = (const float*)d_in[1];
    const float* g1 = (const float*)d_in[2];
    const float* b1 = (const float*)d_in[3];
    const float* A1 = (const float*)d_in[4];
    const float* B1 = (const float*)d_in[5];
    const float* M2 = (const float*)d_in[6];
    const float* g2 = (const float*)d_in[7];
    const float* b2 = (const float*)d_in[8];
    const float* P2 = (const float*)d_in[9];
    const float* R2 = (const float*)d_in[10];
    const float* W3 = (const float*)d_in[11];
    const float* g3 = (const float*)d_in[12];
    const float* b3 = (const float*)d_in[13];
    const float* A3 = (const float*)d_in[14];
    const float* B3 = (const float*)d_in[15];
    const float* R3 = (const float*)d_in[16];

    float* ws = (float*)d_ws;
    float* C1   = ws;                   // 2 x 2,097,152 = 4,194,304
    float* C2   = ws + 4194304;         // 4 x 524,288   = 2,097,152
    float* C3   = ws + 6291456;         // 4,194,304
    float* t    = ws + 10485760;        // 262,144 (4096 x 64)
    float* rsum = ws + 10747904;        // 262,144 (must follow t: overrun pad)
    float* A1T  = ws + 11010048;        // 32,768
    float* A3T  = ws + 11042816;        // 32,768
    unsigned short* us = (unsigned short*)(ws + 11075584);
    unsigned short* xh   = us;                  // 2,097,152 each
    unsigned short* xl   = us + 2097152;
    unsigned short* h1h  = us + 4194304;
    unsigned short* h1l  = us + 6291456;
    unsigned short* W1h  = us + 8388608;        // 262,144 each
    unsigned short* W1l  = us + 8650752;
    unsigned short* Wc2h = us + 8912896;        // 65,536 each (128 x 512)
    unsigned short* Wc2l = us + 8978432;
    unsigned short* Wc3h = us + 9043968;        // 65,536 each (1024 x 64)
    unsigned short* Wc3l = us + 9109504;
    unsigned short* h2h  = us + 9175040;        // 262,144 each (4096 x 64)
    unsigned short* h2l  = us + 9437184;

    dim3 blk(256);

    // 0) convert + transpose
    convk<<<1344, blk, 0, stream>>>(x, W1, M2, R2, W3, R3, A1, A3,
                                    xh, xl, W1h, W1l, Wc2h, Wc2l, Wc3h, Wc3l,
                                    A1T, A3T);

    // 1) C1 = x @ W1^T (split-K=2 -> 1024 blocks); h1 = RN(C1)+x -> planes
    gemm64<<<dim3(8, 64, 2), blk, 0, stream>>>(xh, xl, W1h, W1l, C1, ROWS, 512, 512, 256);
    lnrn<<<1024, blk, 0, stream>>>(C1, C1 + 2097152, 512, x, 512, g1, b1, B1, A1T,
                                   nullptr, h1h, h1l);

    // 2) C2 = h1 @ [M2;R2]^T (split-K=4 -> 512 blocks); t/rsum; h2 = TS
    gemm64<<<dim3(2, 64, 4), blk, 0, stream>>>(h1h, h1l, Wc2h, Wc2l, C2, ROWS, 128, 512, 128);
    lnt<<<1024, blk, 0, stream>>>(C2, g2, b2, t, rsum);
    tsk2<<<512, blk, 0, stream>>>(t, rsum, P2, h2h, h2l);

    // 3) C3 = h2 @ [W3;R3]^T (1024 blocks); out = RN(C3[:,:512]) + C3[:,512:]
    gemm64<<<dim3(16, 64, 1), blk, 0, stream>>>(h2h, h2l, Wc3h, Wc3l, C3, ROWS, 1024, 64, 64);
    lnrn<<<1024, blk, 0, stream>>>(C3, nullptr, 1024, C3 + 512, 1024, g3, b3, B3, A3T,
                                   (float*)d_out, nullptr, nullptr);
}